// Round 8
// baseline (134.766 us; speedup 1.0000x reference)
//
#include <hip/hip_runtime.h>

// FeatureFlowAttention (local_window_attn=1, r=1), b=4, c=128, h=w=128.
// scores(p,p') = x_p^T M x_p' + gamma_p + delta_p' + d, M = Wq^T Wk.
// Pipeline:
//   prep:  M = Wq^T Wk split to bf16 (Mh,Ml); u, v, d.
//   proj:  y = M x via MFMA split-bf16 3-pass; also emits gamma = x.u and
//          delta' = x.v + d per pixel (wave-0 shfl reduction).
//   attn:  FUSED: 8 waves/block, wave = 16-ch group over a 256-px tile
//          (4 px/thread float4 flat-shift), two-phase LDS reduction (36 KB),
//          then in-block softmax + flow gather. No ps intermediate (R7's
//          18.9 MB x2 round-trip eliminated), one fewer dispatch.

#define HW 16384
#define NB 4
#define TOT (NB * HW)   // 65536 pixels

typedef short bf16x8 __attribute__((ext_vector_type(8)));
typedef float f32x4 __attribute__((ext_vector_type(4)));

__device__ __forceinline__ unsigned short f2bf(float f) {   // RNE float->bf16
    unsigned u = __float_as_uint(f);
    return (unsigned short)((u + 0x7fffu + ((u >> 16) & 1u)) >> 16);
}
__device__ __forceinline__ float bf2f(unsigned short s) {
    return __uint_as_float(((unsigned)s) << 16);
}

// ---------------- prep ----------------------------------------------------------
__global__ void prep_kernel(const float* __restrict__ qw, const float* __restrict__ qb,
                            const float* __restrict__ kw, const float* __restrict__ kb,
                            unsigned short* __restrict__ Mh, unsigned short* __restrict__ Ml,
                            float* __restrict__ u, float* __restrict__ v,
                            float* __restrict__ dptr) {
    __shared__ float red[128];
    int bid = blockIdx.x, tid = threadIdx.x;
    if (bid < 16) {
        // M[ci][cj] = sum_co qw[co][ci] * kw[co][cj]; tile: 8 ci x 128 cj
        int ci = bid * 8 + (tid >> 5);
        int cj = (tid & 31) * 4;
        float4 acc = make_float4(0.f, 0.f, 0.f, 0.f);
#pragma unroll 4
        for (int co = 0; co < 128; ++co) {
            float qv = qw[co * 128 + ci];
            float4 kv = *(const float4*)(kw + co * 128 + cj);
            acc.x += qv * kv.x; acc.y += qv * kv.y;
            acc.z += qv * kv.z; acc.w += qv * kv.w;
        }
        int o = ci * 128 + cj;
        float a[4] = {acc.x, acc.y, acc.z, acc.w};
#pragma unroll
        for (int j = 0; j < 4; ++j) {
            unsigned short h = f2bf(a[j]);
            Mh[o + j] = h;
            Ml[o + j] = f2bf(a[j] - bf2f(h));
        }
    } else {
        // u[t] = sum qw[co][t]*kb[co];  v[t] = sum kw[co][t]*qb[co];  d = qb.kb
        int half = tid >> 7, t = tid & 127;
        const float* w  = half ? kw : qw;
        const float* bv = half ? qb : kb;
        float acc = 0.f;
#pragma unroll 4
        for (int co = 0; co < 128; ++co) acc += w[co * 128 + t] * bv[co];
        if (half) v[t] = acc; else u[t] = acc;
        if (!half) red[t] = qb[t] * kb[t];
        __syncthreads();
        if (tid == 0) {
            float dd = 0.f;
            for (int i = 0; i < 128; ++i) dd += red[i];
            *dptr = dd;
        }
    }
}

// ---------------- proj: y = M x via MFMA split-bf16 + gamma/delta maps ----------
// Wave w = cig (ci range cig*32..+32); all 4 waves share blockIdx's 64-px tile.
// Wave 0 also accumulates gamma/delta (shfl-xor 16/32 reduction over q).
// Verified layouts (16x16x32 bf16): A[m=lane&15][k=(lane>>4)*8+j];
// B[k=(lane>>4)*8+j][n=lane&15]; D col=lane&15, row=(lane>>4)*4+reg.
__global__ __launch_bounds__(256, 2)
void proj_kernel(const float* __restrict__ feat, const unsigned short* __restrict__ MhG,
                 const unsigned short* __restrict__ MlG,
                 const float* __restrict__ u, const float* __restrict__ v,
                 const float* __restrict__ dptr, float* __restrict__ y,
                 float* __restrict__ gam, float* __restrict__ del) {
    int tid = threadIdx.x;
    int lane = tid & 63;
    int cig = tid >> 6;
    int ci0 = cig * 32;
    int pxg = blockIdx.x;
    int P0 = pxg * 64;
    int b = P0 >> 14, p0 = P0 & (HW - 1);
    int m = lane & 15, q = lane >> 4;
    const float* xbase = feat + (size_t)b * 128 * HW + p0;

    f32x4 zero = {0.f, 0.f, 0.f, 0.f};
    f32x4 acc[2][4];
#pragma unroll
    for (int t = 0; t < 2; ++t)
#pragma unroll
        for (int s = 0; s < 4; ++s) acc[t][s] = zero;
    float gacc[4] = {0.f, 0.f, 0.f, 0.f};
    float dacc[4] = {0.f, 0.f, 0.f, 0.f};

#pragma unroll
    for (int kc = 0; kc < 4; ++kc) {
        int c0 = kc * 32;
        bf16x8 ah[2], al[2];
#pragma unroll
        for (int t = 0; t < 2; ++t) {
            int roff = (ci0 + t * 16 + m) * 128 + c0 + q * 8;
            ah[t] = *(const bf16x8*)(MhG + roff);
            al[t] = *(const bf16x8*)(MlG + roff);
        }
        float uj[8], vj[8];
        if (cig == 0) {
#pragma unroll
            for (int j = 0; j < 8; ++j) {
                uj[j] = u[c0 + q * 8 + j];
                vj[j] = v[c0 + q * 8 + j];
            }
        }
        bf16x8 bh[4], bl[4];
#pragma unroll
        for (int s = 0; s < 4; ++s) {
            const float* xp = xbase + (size_t)(c0 + q * 8) * HW + s * 16 + m;
            float xv[8];
#pragma unroll
            for (int j = 0; j < 8; ++j) xv[j] = xp[(size_t)j * HW];
            if (cig == 0) {
#pragma unroll
                for (int j = 0; j < 8; ++j) {
                    gacc[s] = fmaf(xv[j], uj[j], gacc[s]);
                    dacc[s] = fmaf(xv[j], vj[j], dacc[s]);
                }
            }
#pragma unroll
            for (int j = 0; j < 8; ++j) {
                unsigned short h = f2bf(xv[j]);
                bh[s][j] = (short)h;
                bl[s][j] = (short)f2bf(xv[j] - bf2f(h));
            }
        }
#pragma unroll
        for (int t = 0; t < 2; ++t)
#pragma unroll
            for (int s = 0; s < 4; ++s) {
                acc[t][s] = __builtin_amdgcn_mfma_f32_16x16x32_bf16(ah[t], bh[s], acc[t][s], 0, 0, 0);
                acc[t][s] = __builtin_amdgcn_mfma_f32_16x16x32_bf16(ah[t], bl[s], acc[t][s], 0, 0, 0);
                acc[t][s] = __builtin_amdgcn_mfma_f32_16x16x32_bf16(al[t], bh[s], acc[t][s], 0, 0, 0);
            }
    }

    // gamma/delta: reduce over q (lanes m, m+16, m+32, m+48 share a pixel)
    if (cig == 0) {
        float dconst = *dptr;
#pragma unroll
        for (int s = 0; s < 4; ++s) {
            float g = gacc[s], dd = dacc[s];
            g += __shfl_xor(g, 16);  g += __shfl_xor(g, 32);
            dd += __shfl_xor(dd, 16); dd += __shfl_xor(dd, 32);
            if (q == 0) {
                gam[(size_t)b * HW + p0 + s * 16 + m] = g;
                del[(size_t)b * HW + p0 + s * 16 + m] = dd + dconst;
            }
        }
    }

    int rg = lane >> 4, col = lane & 15;
#pragma unroll
    for (int t = 0; t < 2; ++t)
#pragma unroll
        for (int s = 0; s < 4; ++s) {
            float* yp = y + ((size_t)b * 128 + ci0 + t * 16 + rg * 4) * HW + p0 + s * 16 + col;
#pragma unroll
            for (int r = 0; r < 4; ++r) yp[(size_t)r * HW] = acc[t][s][r];
        }
}

// ---------------- attn (fused): scores + softmax + flow gather ------------------
// 512 thr = 8 waves; wave = one 16-ch group (c0 = wid*16) over the block's
// 256-px flat tile; thread = 4 px (float4). Two-phase LDS reduce into
// sred[4][9][256] (36 KB): waves 4-7 store, waves 0-3 add in place, then
// threads 0-255 finalize one pixel each (validity mask, softmax, flow avg).
// Flat-shift OOB reads hit adjacent ws regions (garbage, masked in finalize).
__global__ __launch_bounds__(512, 1)
void attn_fused_kernel(const float* __restrict__ feat, const float* __restrict__ y,
                       const float* __restrict__ gam, const float* __restrict__ del,
                       const float* __restrict__ flow, float* __restrict__ out) {
    __shared__ float sred[4][9][256];

    int tid = threadIdx.x;
    int wid = tid >> 6, lane = tid & 63;
    int P0 = blockIdx.x * 256;            // 256-px tile, same batch (256 | HW)
    int P = P0 + lane * 4;
    int b = P >> 14, p = P & (HW - 1);
    int c0 = wid * 16;
    const float* xb = feat + ((size_t)b * 128 + c0) * HW + p;
    const float* yb = y + ((size_t)b * 128 + c0) * HW + p;

    f32x4 s[9];
#pragma unroll
    for (int k = 0; k < 9; ++k) s[k] = (f32x4){0.f, 0.f, 0.f, 0.f};

#pragma unroll 2
    for (int c = 0; c < 16; ++c) {
        float4 xv = *(const float4*)(xb + (size_t)c * HW);
        const float* yc = yb + (size_t)c * HW;
#pragma unroll
        for (int dy = 0; dy < 3; ++dy) {
            const float* yr = yc + (dy - 1) * 128;
            float4 mm = *(const float4*)(yr);
            float lm = yr[-1];
            float rp = yr[4];
            int k = dy * 3;
            s[k][0] += xv.x * lm;     s[k][1] += xv.y * mm.x;
            s[k][2] += xv.z * mm.y;   s[k][3] += xv.w * mm.z;
            s[k+1][0] += xv.x * mm.x; s[k+1][1] += xv.y * mm.y;
            s[k+1][2] += xv.z * mm.z; s[k+1][3] += xv.w * mm.w;
            s[k+2][0] += xv.x * mm.y; s[k+2][1] += xv.y * mm.z;
            s[k+2][2] += xv.z * mm.w; s[k+2][3] += xv.w * rp;
        }
    }

    if (wid >= 4) {
#pragma unroll
        for (int k = 0; k < 9; ++k)
            *(f32x4*)&sred[wid - 4][k][lane * 4] = s[k];
    }
    __syncthreads();
    if (wid < 4) {
#pragma unroll
        for (int k = 0; k < 9; ++k) {
            f32x4 t = *(const f32x4*)&sred[wid][k][lane * 4];
            t += s[k];
            *(f32x4*)&sred[wid][k][lane * 4] = t;
        }
    }
    __syncthreads();

    if (tid < 256) {
        int Pf = P0 + tid;
        int bf_ = Pf >> 14, pf = Pf & (HW - 1);
        int row = pf >> 7, col = pf & 127;
        const float inv = 0.08838834764831845f;   // 1/sqrt(128)
        float g = gam[Pf];

        float sc[9];
        float mx = -1e30f;
#pragma unroll
        for (int k = 0; k < 9; ++k) {
            int dy = k / 3 - 1, dx = (k % 3) - 1;
            bool valid = ((unsigned)(row + dy) < 128u) && ((unsigned)(col + dx) < 128u);
            float ssum = sred[0][k][tid] + sred[1][k][tid]
                       + sred[2][k][tid] + sred[3][k][tid];
            int Pn = Pf + dy * 128 + dx;
            Pn = max(0, min(TOT - 1, Pn));        // clamp (unused when invalid)
            float sv = valid ? (ssum + g + del[Pn]) * inv : 0.f;
            sc[k] = sv;
            mx = fmaxf(mx, sv);
        }
        float e[9], sum = 0.f;
#pragma unroll
        for (int k = 0; k < 9; ++k) { e[k] = __expf(sc[k] - mx); sum += e[k]; }
        float rs = 1.f / sum;

        float o0 = 0.f, o1 = 0.f;
#pragma unroll
        for (int k = 0; k < 9; ++k) {
            int dy = k / 3 - 1, dx = (k % 3) - 1;
            bool valid = ((unsigned)(row + dy) < 128u) && ((unsigned)(col + dx) < 128u);
            float pr = valid ? e[k] * rs : 0.f;
            int fi0 = bf_ * 2 * HW + pf + dy * 128 + dx;
            fi0 = max(0, min(2 * TOT - 1, fi0));
            int fi1 = (bf_ * 2 + 1) * HW + pf + dy * 128 + dx;
            fi1 = max(0, min(2 * TOT - 1, fi1));
            o0 += pr * flow[fi0];
            o1 += pr * flow[fi1];
        }
        out[(size_t)(bf_ * 2) * HW + pf] = o0;
        out[(size_t)(bf_ * 2 + 1) * HW + pf] = o1;
    }
}

extern "C" void kernel_launch(void* const* d_in, const int* in_sizes, int n_in,
                              void* d_out, int out_size, void* d_ws, size_t ws_size,
                              hipStream_t stream) {
    const float* feat = (const float*)d_in[0];
    const float* flow = (const float*)d_in[1];
    const float* qw = (const float*)d_in[2];
    const float* qb = (const float*)d_in[3];
    const float* kw = (const float*)d_in[4];
    const float* kb = (const float*)d_in[5];

    float* ws = (float*)d_ws;
    float* u = ws;                              // 128
    float* v = ws + 128;                        // 128
    float* dptr = ws + 256;                     // 1 (pad to 512)
    unsigned short* Mh = (unsigned short*)(ws + 512);    // 16384 bf16
    unsigned short* Ml = (unsigned short*)(ws + 8704);   // 16384 bf16
    float* y = ws + 16896;                      // 4*128*16384 = 8388608
    float* gam = ws + 8405760;                  // (+256 pad) 65536
    float* del = ws + 8471296;                  // 65536
    float* out = (float*)d_out;

    prep_kernel<<<17, 256, 0, stream>>>(qw, qb, kw, kb, Mh, Ml, u, v, dptr);
    proj_kernel<<<1024, 256, 0, stream>>>(feat, Mh, Ml, u, v, dptr, y, gam, del);
    attn_fused_kernel<<<256, 512, 0, stream>>>(feat, y, gam, del, flow, out);
}

// Round 9
// 127.547 us; speedup vs baseline: 1.0566x; 1.0566x over previous
//
#include <hip/hip_runtime.h>

// FeatureFlowAttention (local_window_attn=1, r=1), b=4, c=128, h=w=128.
// scores(p,p') = x_p^T M x_p' + gamma_p + delta_p' + d, M = Wq^T Wk.
// Pipeline (measured-best config, R5):
//   prep:    M = Wq^T Wk split to bf16 (Mh,Ml); u, v, d.
//   proj:    y = M x via MFMA split-bf16 3-pass (mh*xh + mh*xl + ml*xh), zero LDS,
//            NO extra folds (gamma fold in proj measured -5us regression R6-R8).
//   partial: flat 9-shift partial scores (4-way channel split) + gamma/delta
//            partials (free: x already in registers).
//   final:   sum partials, validity-mask, softmax, flow gather.

#define HW 16384
#define NB 4
#define TOT (NB * HW)   // 65536 pixels

typedef short bf16x8 __attribute__((ext_vector_type(8)));
typedef float f32x4 __attribute__((ext_vector_type(4)));

__device__ __forceinline__ unsigned short f2bf(float f) {   // RNE float->bf16
    unsigned u = __float_as_uint(f);
    return (unsigned short)((u + 0x7fffu + ((u >> 16) & 1u)) >> 16);
}
__device__ __forceinline__ float bf2f(unsigned short s) {
    return __uint_as_float(((unsigned)s) << 16);
}

// ---------------- prep ----------------------------------------------------------
__global__ void prep_kernel(const float* __restrict__ qw, const float* __restrict__ qb,
                            const float* __restrict__ kw, const float* __restrict__ kb,
                            unsigned short* __restrict__ Mh, unsigned short* __restrict__ Ml,
                            float* __restrict__ u, float* __restrict__ v,
                            float* __restrict__ dptr) {
    __shared__ float red[128];
    int bid = blockIdx.x, tid = threadIdx.x;
    if (bid < 16) {
        // M[ci][cj] = sum_co qw[co][ci] * kw[co][cj]; tile: 8 ci x 128 cj
        int ci = bid * 8 + (tid >> 5);
        int cj = (tid & 31) * 4;
        float4 acc = make_float4(0.f, 0.f, 0.f, 0.f);
#pragma unroll 4
        for (int co = 0; co < 128; ++co) {
            float qv = qw[co * 128 + ci];
            float4 kv = *(const float4*)(kw + co * 128 + cj);
            acc.x += qv * kv.x; acc.y += qv * kv.y;
            acc.z += qv * kv.z; acc.w += qv * kv.w;
        }
        int o = ci * 128 + cj;
        float a[4] = {acc.x, acc.y, acc.z, acc.w};
#pragma unroll
        for (int j = 0; j < 4; ++j) {
            unsigned short h = f2bf(a[j]);
            Mh[o + j] = h;
            Ml[o + j] = f2bf(a[j] - bf2f(h));
        }
    } else {
        // u[t] = sum qw[co][t]*kb[co];  v[t] = sum kw[co][t]*qb[co];  d = qb.kb
        int half = tid >> 7, t = tid & 127;
        const float* w  = half ? kw : qw;
        const float* bv = half ? qb : kb;
        float acc = 0.f;
#pragma unroll 4
        for (int co = 0; co < 128; ++co) acc += w[co * 128 + t] * bv[co];
        if (half) v[t] = acc; else u[t] = acc;
        if (!half) red[t] = qb[t] * kb[t];
        __syncthreads();
        if (tid == 0) {
            float dd = 0.f;
            for (int i = 0; i < 128; ++i) dd += red[i];
            *dptr = dd;
        }
    }
}

// ---------------- proj: y = M x via MFMA split-bf16, zero LDS -------------------
// Wave W: cig = W&3 (ci range cig*32..+32), pxg = W>>2 (64-px tile, within one image).
// Per 32-k chunk: A = 2 ci-tiles x {h,l} as b128 from global Mh/Ml (L2-hot);
// B = 4 px-tiles built from 8 coalesced fp32 loads + in-register bf16 split.
// Verified layouts (16x16x32 bf16): A[m=lane&15][k=(lane>>4)*8+j];
// B[k=(lane>>4)*8+j][n=lane&15]; D col=lane&15, row=(lane>>4)*4+reg.
__global__ __launch_bounds__(256, 2)
void proj_kernel(const float* __restrict__ feat, const unsigned short* __restrict__ MhG,
                 const unsigned short* __restrict__ MlG, float* __restrict__ y) {
    int tid = threadIdx.x;
    int W = blockIdx.x * 4 + (tid >> 6);
    int lane = tid & 63;
    int cig = W & 3, pxg = W >> 2;
    int ci0 = cig * 32;
    int P0 = pxg * 64;
    int b = P0 >> 14, p0 = P0 & (HW - 1);
    int m = lane & 15, q = lane >> 4;
    const float* xbase = feat + (size_t)b * 128 * HW + p0;

    f32x4 zero = {0.f, 0.f, 0.f, 0.f};
    f32x4 acc[2][4];
#pragma unroll
    for (int t = 0; t < 2; ++t)
#pragma unroll
        for (int s = 0; s < 4; ++s) acc[t][s] = zero;

#pragma unroll
    for (int kc = 0; kc < 4; ++kc) {
        int c0 = kc * 32;
        bf16x8 ah[2], al[2];
#pragma unroll
        for (int t = 0; t < 2; ++t) {
            int roff = (ci0 + t * 16 + m) * 128 + c0 + q * 8;
            ah[t] = *(const bf16x8*)(MhG + roff);
            al[t] = *(const bf16x8*)(MlG + roff);
        }
        bf16x8 bh[4], bl[4];
#pragma unroll
        for (int s = 0; s < 4; ++s) {
            const float* xp = xbase + (size_t)(c0 + q * 8) * HW + s * 16 + m;
            float xv[8];
#pragma unroll
            for (int j = 0; j < 8; ++j) xv[j] = xp[(size_t)j * HW];
#pragma unroll
            for (int j = 0; j < 8; ++j) {
                unsigned short h = f2bf(xv[j]);
                bh[s][j] = (short)h;
                bl[s][j] = (short)f2bf(xv[j] - bf2f(h));
            }
        }
#pragma unroll
        for (int t = 0; t < 2; ++t)
#pragma unroll
            for (int s = 0; s < 4; ++s) {
                acc[t][s] = __builtin_amdgcn_mfma_f32_16x16x32_bf16(ah[t], bh[s], acc[t][s], 0, 0, 0);
                acc[t][s] = __builtin_amdgcn_mfma_f32_16x16x32_bf16(ah[t], bl[s], acc[t][s], 0, 0, 0);
                acc[t][s] = __builtin_amdgcn_mfma_f32_16x16x32_bf16(al[t], bh[s], acc[t][s], 0, 0, 0);
            }
    }

    int rg = lane >> 4, col = lane & 15;
#pragma unroll
    for (int t = 0; t < 2; ++t)
#pragma unroll
        for (int s = 0; s < 4; ++s) {
            float* yp = y + ((size_t)b * 128 + ci0 + t * 16 + rg * 4) * HW + p0 + s * 16 + col;
#pragma unroll
            for (int r = 0; r < 4; ++r) yp[(size_t)r * HW] = acc[t][s][r];
        }
}

// ---------------- attn_partial: 9-shift partial scores + gamma/delta partials ----
// 4-way channel split, 2 px/thread float2 -> 512 blocks (2 waves/SIMD).
// Row-edge wrap-around garbage is discarded in attn_final by index validity.
__global__ __launch_bounds__(256, 4)
void attn_partial_kernel(const float* __restrict__ feat, const float* __restrict__ y,
                         const float* __restrict__ u, const float* __restrict__ v,
                         float* __restrict__ ps, float* __restrict__ gd) {
    int tid = threadIdx.x;
    int blk = blockIdx.x;                 // cg*128 + tileblock
    int cg = blk >> 7;
    int pp = (blk & 127) * 256 + tid;     // pixel-pair index 0..32767
    int P = pp * 2;                       // flat pixel (b*HW+p), even
    int b = P >> 14;
    int p = P & (HW - 1);
    const float* xb = feat + ((size_t)b * 128 + cg * 32) * HW + p;
    const float* yb = y + ((size_t)b * 128 + cg * 32) * HW + p;

    float s0[9], s1[9];
#pragma unroll
    for (int k = 0; k < 9; ++k) { s0[k] = 0.f; s1[k] = 0.f; }
    float g0 = 0.f, g1 = 0.f, d0 = 0.f, d1 = 0.f;

#pragma unroll 2
    for (int c = 0; c < 32; ++c) {
        float2 xv = *(const float2*)(xb + (size_t)c * HW);
        float uc = u[cg * 32 + c], vc = v[cg * 32 + c];
        g0 += xv.x * uc; g1 += xv.y * uc;
        d0 += xv.x * vc; d1 += xv.y * vc;
        const float* yc = yb + (size_t)c * HW;
#pragma unroll
        for (int dy = 0; dy < 3; ++dy) {
            const float* yr = yc + (dy - 1) * 128;
            float2 a  = *(const float2*)(yr - 2);   // cols p-2,p-1
            float2 bb = *(const float2*)(yr);       // cols p,  p+1
            float2 cc = *(const float2*)(yr + 2);   // cols p+2,p+3
            s0[dy * 3 + 0] += xv.x * a.y;   s1[dy * 3 + 0] += xv.y * bb.x;
            s0[dy * 3 + 1] += xv.x * bb.x;  s1[dy * 3 + 1] += xv.y * bb.y;
            s0[dy * 3 + 2] += xv.x * bb.y;  s1[dy * 3 + 2] += xv.y * cc.x;
        }
    }
    float* pso = ps + (size_t)cg * 9 * TOT + P;
#pragma unroll
    for (int k = 0; k < 9; ++k)
        *(float2*)(pso + (size_t)k * TOT) = make_float2(s0[k], s1[k]);
    *(float2*)(gd + (size_t)(cg * 2 + 0) * TOT + P) = make_float2(g0, g1);
    *(float2*)(gd + (size_t)(cg * 2 + 1) * TOT + P) = make_float2(d0, d1);
}

// ---------------- attn_final ----------------------------------------------------
__global__ __launch_bounds__(256, 4)
void attn_final_kernel(const float* __restrict__ flow, const float* __restrict__ ps,
                       const float* __restrict__ gd, const float* __restrict__ dptr,
                       float* __restrict__ out) {
    int P = blockIdx.x * 256 + threadIdx.x;   // 0..65535
    int b = P >> 14, p = P & (HW - 1);
    int row = p >> 7, col = p & 127;
    const float inv = 0.08838834764831845f;   // 1/sqrt(128)
    float dconst = *dptr;

    float g = 0.f;
#pragma unroll
    for (int cg = 0; cg < 4; ++cg) g += gd[(size_t)(cg * 2) * TOT + P];

    float sc[9];
    float mx = -1e30f;
#pragma unroll
    for (int k = 0; k < 9; ++k) {
        int dy = k / 3 - 1, dx = (k % 3) - 1;
        bool valid = ((unsigned)(row + dy) < 128u) && ((unsigned)(col + dx) < 128u);
        float ssum = 0.f;
#pragma unroll
        for (int cg = 0; cg < 4; ++cg) ssum += ps[(size_t)(cg * 9 + k) * TOT + P];
        int Pn = P + dy * 128 + dx;
        Pn = max(0, min(TOT - 1, Pn));
        float dsum = dconst;
#pragma unroll
        for (int cg = 0; cg < 4; ++cg) dsum += gd[(size_t)(cg * 2 + 1) * TOT + Pn];
        float s = valid ? (ssum + g + dsum) * inv : 0.f;
        sc[k] = s;
        mx = fmaxf(mx, s);
    }
    float e[9], sum = 0.f;
#pragma unroll
    for (int k = 0; k < 9; ++k) { e[k] = __expf(sc[k] - mx); sum += e[k]; }
    float rs = 1.f / sum;

    float o0 = 0.f, o1 = 0.f;
#pragma unroll
    for (int k = 0; k < 9; ++k) {
        int dy = k / 3 - 1, dx = (k % 3) - 1;
        bool valid = ((unsigned)(row + dy) < 128u) && ((unsigned)(col + dx) < 128u);
        float pr = valid ? e[k] * rs : 0.f;
        int fi0 = b * 2 * HW + p + dy * 128 + dx;
        fi0 = max(0, min(2 * TOT - 1, fi0));
        int fi1 = (b * 2 + 1) * HW + p + dy * 128 + dx;
        fi1 = max(0, min(2 * TOT - 1, fi1));
        o0 += pr * flow[fi0];
        o1 += pr * flow[fi1];
    }
    out[(size_t)(b * 2) * HW + p] = o0;
    out[(size_t)(b * 2 + 1) * HW + p] = o1;
}

extern "C" void kernel_launch(void* const* d_in, const int* in_sizes, int n_in,
                              void* d_out, int out_size, void* d_ws, size_t ws_size,
                              hipStream_t stream) {
    const float* feat = (const float*)d_in[0];
    const float* flow = (const float*)d_in[1];
    const float* qw = (const float*)d_in[2];
    const float* qb = (const float*)d_in[3];
    const float* kw = (const float*)d_in[4];
    const float* kb = (const float*)d_in[5];

    float* ws = (float*)d_ws;
    float* u = ws;                              // 128
    float* v = ws + 128;                        // 128
    float* dptr = ws + 256;                     // 1 (pad to 512)
    unsigned short* Mh = (unsigned short*)(ws + 512);    // 16384 bf16
    unsigned short* Ml = (unsigned short*)(ws + 8704);   // 16384 bf16
    float* y = ws + 16896;                      // 4*128*16384 = 8388608
    float* ps = ws + 8405760;                   // (+256 pad) 4*9*65536 = 2359296
    float* gd = ws + 10765056;                  // 4*2*65536 = 524288
    float* out = (float*)d_out;

    prep_kernel<<<17, 256, 0, stream>>>(qw, qb, kw, kb, Mh, Ml, u, v, dptr);
    proj_kernel<<<1024, 256, 0, stream>>>(feat, Mh, Ml, y);
    attn_partial_kernel<<<512, 256, 0, stream>>>(feat, y, u, v, ps, gd);
    attn_final_kernel<<<256, 256, 0, stream>>>(flow, ps, gd, dptr, out);
}